// Round 5
// baseline (346.038 us; speedup 1.0000x reference)
//
#include <hip/hip_runtime.h>
#include <hip/hip_cooperative_groups.h>

namespace cg = cooperative_groups;

// TensorTrain: out[b] = first(x0) . M0(x1) . ... . M29(x30) . last(x31)
// with R=16, D=32, B=262144, selection bits in {0,1}.
//
// Meet-in-the-middle: out = V16[p] . W16[s], p = x0..x15 (MSB first),
// s = x16..x31. Rounds 0-4 established: kernel content is cheap (<45 us
// each); the remaining lever is dispatch count (~6 us per boundary:
// 4 disp = 123.0, 2 disp = 111.4, 3 disp = 117.4). This version fuses
// everything into ONE cooperative dispatch with two grid.sync()s:
//   phase 1: all 512 blocks pack their own 512 elements' (p,s) into
//            REGISTERS (no global pk round-trip); blocks 0..33 also build
//            byte tables P8 (M7..14), Q8 (M15..22), V8 (first@M0..6),
//            W8 (M23..29@last) from bit-deinterleaved LDS cores.
//   sync    (threadfence + grid.sync for cross-XCD visibility)
//   phase 2: blocks 0..255: V16[g*256+t] = V8[g] @ P8[t];
//            blocks 256..511: W16[g*256+t] = Q8[g] @ W8[t] (Q8 in LDS).
//   sync
//   phase 3: per element: two 64 B gathers + 16-wide dot from registers.
// Rolled-loop discipline kept from round 3 (I-cache: 90 KB straight-line
// bodies were fetch-bound at 7% VALUBusy).

#define R 16
#define TT_D 32
#define BATCH 262144
#define NBLK 512
#define EPB (BATCH / NBLK)              // 512 elements per block, 2/thread

// workspace layout, in floats
#define OFF_P8   0                      // 256 x 16 x 16
#define OFF_Q8   65536                  // 256 x 16 x 16
#define OFF_V8   (OFF_Q8 + 65536)       // 256 x 16
#define OFF_W8   (OFF_V8 + 4096)        // 256 x 16
#define OFF_V16  (OFF_W8 + 4096)        // 65536 x 16 (4 MB)
#define OFF_W16  (OFF_V16 + 1048576)    // 65536 x 16 (4 MB)
#define WS_FLOATS (OFF_W16 + 1048576)   // ~8.9 MB

// u (registers, row-vec) = u @ M, M row-major 16x16 (LDS or global).
// Inner fully unrolled: static indexing keeps u/nv in VGPRs.
__device__ __forceinline__ void rowvec_mat(const float* __restrict__ M,
                                           float* __restrict__ u) {
    float nv[R];
    #pragma unroll
    for (int s = 0; s < R; s++) nv[s] = 0.f;
    #pragma unroll
    for (int t2 = 0; t2 < R; t2++) {
        const float a = u[t2];
        #pragma unroll
        for (int s = 0; s < R; s++) nv[s] += a * M[t2 * 16 + s];
    }
    #pragma unroll
    for (int s = 0; s < R; s++) u[s] = nv[s];
}

// w (registers, col-vec) = M @ w.
__device__ __forceinline__ void mat_colvec(const float* __restrict__ M,
                                           float* __restrict__ w) {
    float nw[R];
    #pragma unroll
    for (int r2 = 0; r2 < R; r2++) {
        float a = 0.f;
        #pragma unroll
        for (int k = 0; k < R; k++) a += M[r2 * 16 + k] * w[k];
        nw[r2] = a;
    }
    #pragma unroll
    for (int r2 = 0; r2 < R; r2++) w[r2] = nw[r2];
}

// Pack one element's 32 bits into (p<<16)|s, MSB-first per half.
__device__ __forceinline__ unsigned pack_elem(const int* __restrict__ X, int b) {
    const int4* Xr = (const int4*)(X + (size_t)b * TT_D);
    unsigned v = 0;
    #pragma unroll
    for (int q = 0; q < 8; q++) {
        const int4 c = Xr[q];
        v = (v << 4) | ((unsigned)(c.x & 1) << 3) | ((unsigned)(c.y & 1) << 2)
                     | ((unsigned)(c.z & 1) << 1) | (unsigned)(c.w & 1);
    }
    return v;
}

// ---------------------------------------------------------------------------
__global__ __launch_bounds__(256, 2) void tt_fused(const int* __restrict__ X,
                                                   const float* __restrict__ cf,
                                                   const float* __restrict__ cm,
                                                   const float* __restrict__ cl,
                                                   float* __restrict__ ws,
                                                   float* __restrict__ out) {
    __shared__ float scm[8 * 512];      // 16 KB: staged cores / phase-2 sQ
    const int blk = blockIdx.x;
    const int t = threadIdx.x;
    cg::grid_group grid = cg::this_grid();

    // ---- phase 1a: pack this block's 512 elements into registers ----
    const unsigned pk0 = pack_elem(X, blk * EPB + t);
    const unsigned pk1 = pack_elem(X, blk * EPB + 256 + t);

    // ---- phase 1b: blocks 0..33 build byte tables ----
    if (blk < 34) {
        int cbase, ncore;
        if (blk < 16)       { cbase = 7;  ncore = 8; }   // P8: M7..M14
        else if (blk < 32)  { cbase = 15; ncore = 8; }   // Q8: M15..M22
        else if (blk == 32) { cbase = 0;  ncore = 7; }   // V8: M0..M6
        else                { cbase = 23; ncore = 7; }   // W8: M23..M29
        const float2* cm2 = (const float2*)(cm + cbase * 512);
        for (int j = t; j < ncore * 256; j += 256) {
            const float2 vv = cm2[j];                    // coalesced 8B loads
            const int ci = j >> 8, idx = j & 255;
            scm[ci * 512 + idx] = vv.x;                  // bit-0 plane
            scm[ci * 512 + 256 + idx] = vv.y;            // bit-1 plane
        }
        __syncthreads();

        if (blk < 32) {
            // P8/Q8[e] row r: product of 8 staged cores, bits of e MSB-first.
            const bool isP = (blk < 16);
            const int e = (isP ? blk : blk - 16) * 16 + (t >> 4), r = t & 15;
            float u[R];
            const float* M0 = scm + ((e >> 7) & 1) * 256;
            #pragma unroll
            for (int s = 0; s < R; s++) u[s] = M0[r * 16 + s];
            for (int k = 1; k < 8; k++)
                rowvec_mat(scm + k * 512 + ((e >> (7 - k)) & 1) * 256, u);
            float* o = ws + (isP ? OFF_P8 : OFF_Q8) + e * 256 + r * 16;
            #pragma unroll
            for (int s = 0; s < R; s++) o[s] = u[s];
        } else if (blk == 32) {
            // V8[e] = first(x0) @ M0(x1) @ ... @ M6(x7), e = t.
            const int e = t;
            float u[R];
            #pragma unroll
            for (int s = 0; s < R; s++) u[s] = cf[s * 2 + ((e >> 7) & 1)];
            for (int k = 0; k < 7; k++)
                rowvec_mat(scm + k * 512 + ((e >> (6 - k)) & 1) * 256, u);
            float* o = ws + OFF_V8 + e * 16;
            #pragma unroll
            for (int s = 0; s < R; s++) o[s] = u[s];
        } else {
            // W8[e] = M23(x24) @ ... @ M29(x30) @ last(x31), e = t.
            const int e = t;
            float w[R];
            #pragma unroll
            for (int r2 = 0; r2 < R; r2++) w[r2] = cl[r2 * 2 + (e & 1)];
            for (int j = 6; j >= 0; j--)
                mat_colvec(scm + j * 512 + ((e >> (7 - j)) & 1) * 256, w);
            float* o = ws + OFF_W8 + e * 16;
            #pragma unroll
            for (int r2 = 0; r2 < R; r2++) o[r2] = w[r2];
        }
    }

    __threadfence();                    // device-scope: cross-XCD visibility
    grid.sync();

    // ---- phase 2: expand byte tables to 16-bit tables ----
    if (blk < 256) {
        // V16[blk*256 + t] = V8[blk] @ P8[t]; v8 block-uniform 64 B.
        float u[R];
        const float* v8 = ws + OFF_V8 + blk * 16;
        #pragma unroll
        for (int k = 0; k < R; k++) u[k] = v8[k];
        rowvec_mat(ws + OFF_P8 + t * 256, u);
        float* o = ws + OFF_V16 + (size_t)(blk * 256 + t) * 16;
        #pragma unroll
        for (int s = 0; s < R; s++) o[s] = u[s];
    } else {
        // W16[(blk-256)*256 + t] = Q8[blk-256] @ W8[t]; Q8 staged in LDS.
        const int hi = blk - 256;
        __syncthreads();                // scm reuse: phase-1 readers done
        scm[t] = ws[OFF_Q8 + hi * 256 + t];
        __syncthreads();
        float w[R];
        const float* w8 = ws + OFF_W8 + t * 16;
        #pragma unroll
        for (int k = 0; k < R; k++) w[k] = w8[k];
        mat_colvec(scm, w);
        float* o = ws + OFF_W16 + (size_t)(hi * 256 + t) * 16;
        #pragma unroll
        for (int r2 = 0; r2 < R; r2++) o[r2] = w[r2];
    }

    __threadfence();
    grid.sync();

    // ---- phase 3: gather own 2 elements from register-held indices ----
    {
        const float4* v = (const float4*)(ws + OFF_V16 + (size_t)(pk0 >> 16) * 16);
        const float4* w = (const float4*)(ws + OFF_W16 + (size_t)(pk0 & 0xffffu) * 16);
        float acc = 0.f;
        #pragma unroll
        for (int k = 0; k < 4; k++) {
            const float4 a = v[k], c = w[k];
            acc += a.x * c.x + a.y * c.y + a.z * c.z + a.w * c.w;
        }
        out[blk * EPB + t] = acc;
    }
    {
        const float4* v = (const float4*)(ws + OFF_V16 + (size_t)(pk1 >> 16) * 16);
        const float4* w = (const float4*)(ws + OFF_W16 + (size_t)(pk1 & 0xffffu) * 16);
        float acc = 0.f;
        #pragma unroll
        for (int k = 0; k < 4; k++) {
            const float4 a = v[k], c = w[k];
            acc += a.x * c.x + a.y * c.y + a.z * c.z + a.w * c.w;
        }
        out[blk * EPB + 256 + t] = acc;
    }
}

// ---------------------------------------------------------------------------
// Fallback path (3 dispatches, round-4 structure) — used only if the
// cooperative launch is rejected or ws is too small.
__global__ __launch_bounds__(256) void tt_stage1(const int* __restrict__ X,
                                                 const float* __restrict__ cf,
                                                 const float* __restrict__ cm,
                                                 const float* __restrict__ cl,
                                                 float* __restrict__ ws,
                                                 unsigned* __restrict__ pk) {
    __shared__ float scm[8 * 512];
    const int blk = blockIdx.x;
    const int t = threadIdx.x;
    if (blk < 34) {
        int cbase, ncore;
        if (blk < 16)       { cbase = 7;  ncore = 8; }
        else if (blk < 32)  { cbase = 15; ncore = 8; }
        else if (blk == 32) { cbase = 0;  ncore = 7; }
        else                { cbase = 23; ncore = 7; }
        const float2* cm2 = (const float2*)(cm + cbase * 512);
        for (int j = t; j < ncore * 256; j += 256) {
            const float2 vv = cm2[j];
            const int ci = j >> 8, idx = j & 255;
            scm[ci * 512 + idx] = vv.x;
            scm[ci * 512 + 256 + idx] = vv.y;
        }
        __syncthreads();
        if (blk < 32) {
            const bool isP = (blk < 16);
            const int e = (isP ? blk : blk - 16) * 16 + (t >> 4), r = t & 15;
            float u[R];
            const float* M0 = scm + ((e >> 7) & 1) * 256;
            #pragma unroll
            for (int s = 0; s < R; s++) u[s] = M0[r * 16 + s];
            for (int k = 1; k < 8; k++)
                rowvec_mat(scm + k * 512 + ((e >> (7 - k)) & 1) * 256, u);
            float* o = ws + (isP ? OFF_P8 : OFF_Q8) + e * 256 + r * 16;
            #pragma unroll
            for (int s = 0; s < R; s++) o[s] = u[s];
        } else if (blk == 32) {
            const int e = t;
            float u[R];
            #pragma unroll
            for (int s = 0; s < R; s++) u[s] = cf[s * 2 + ((e >> 7) & 1)];
            for (int k = 0; k < 7; k++)
                rowvec_mat(scm + k * 512 + ((e >> (6 - k)) & 1) * 256, u);
            float* o = ws + OFF_V8 + e * 16;
            #pragma unroll
            for (int s = 0; s < R; s++) o[s] = u[s];
        } else {
            const int e = t;
            float w[R];
            #pragma unroll
            for (int r2 = 0; r2 < R; r2++) w[r2] = cl[r2 * 2 + (e & 1)];
            for (int j = 6; j >= 0; j--)
                mat_colvec(scm + j * 512 + ((e >> (7 - j)) & 1) * 256, w);
            float* o = ws + OFF_W8 + e * 16;
            #pragma unroll
            for (int r2 = 0; r2 < R; r2++) o[r2] = w[r2];
        }
    } else {
        const int stride = (1024 - 34) * 256;
        for (int b = (blk - 34) * 256 + t; b < BATCH; b += stride)
            pk[b] = pack_elem(X, b);
    }
}

__global__ __launch_bounds__(256) void tt_stage2(float* __restrict__ ws) {
    __shared__ float sQ[256];
    const int blk = blockIdx.x;
    const int t = threadIdx.x;
    if (blk < 256) {
        float u[R];
        const float* v8 = ws + OFF_V8 + blk * 16;
        #pragma unroll
        for (int k = 0; k < R; k++) u[k] = v8[k];
        rowvec_mat(ws + OFF_P8 + t * 256, u);
        float* o = ws + OFF_V16 + (size_t)(blk * 256 + t) * 16;
        #pragma unroll
        for (int s = 0; s < R; s++) o[s] = u[s];
    } else {
        const int hi = blk - 256;
        sQ[t] = ws[OFF_Q8 + hi * 256 + t];
        __syncthreads();
        float w[R];
        const float* w8 = ws + OFF_W8 + t * 16;
        #pragma unroll
        for (int k = 0; k < R; k++) w[k] = w8[k];
        mat_colvec(sQ, w);
        float* o = ws + OFF_W16 + (size_t)(hi * 256 + t) * 16;
        #pragma unroll
        for (int r2 = 0; r2 < R; r2++) o[r2] = w[r2];
    }
}

__global__ __launch_bounds__(256) void tt_gather(const float* __restrict__ ws,
                                                 const unsigned* __restrict__ pk,
                                                 float* __restrict__ out) {
    const int b = blockIdx.x * 256 + threadIdx.x;
    const unsigned v2 = pk[b];
    const float4* v = (const float4*)(ws + OFF_V16 + (size_t)(v2 >> 16) * 16);
    const float4* w = (const float4*)(ws + OFF_W16 + (size_t)(v2 & 0xffffu) * 16);
    float acc = 0.f;
    #pragma unroll
    for (int k = 0; k < 4; k++) {
        const float4 a = v[k], c = w[k];
        acc += a.x * c.x + a.y * c.y + a.z * c.z + a.w * c.w;
    }
    out[b] = acc;
}

// ---------------------------------------------------------------------------
// Last-resort fallback: direct per-thread chain (needs no ws).
__global__ __launch_bounds__(256) void tt_direct(const int* __restrict__ X,
                                                 const float* __restrict__ cf,
                                                 const float* __restrict__ cm,
                                                 const float* __restrict__ cl,
                                                 float* __restrict__ out) {
    __shared__ float scm[30 * 16 * 16 * 2];
    for (int i = threadIdx.x; i < 30 * 16 * 16 * 2; i += blockDim.x) scm[i] = cm[i];
    __syncthreads();
    const int b = blockIdx.x * blockDim.x + threadIdx.x;
    if (b >= BATCH) return;
    const int* xr = X + (size_t)b * TT_D;
    float v[R], nv[R];
    const int x0 = xr[0] & 1;
    #pragma unroll
    for (int rr = 0; rr < R; rr++) v[rr] = cf[rr * 2 + x0];
    for (int i = 1; i <= 30; i++) {
        const int bit = xr[i] & 1;
        const float* M = scm + (i - 1) * 512;
        #pragma unroll
        for (int s2 = 0; s2 < R; s2++) {
            float acc = 0.f;
            #pragma unroll
            for (int rr = 0; rr < R; rr++) acc += v[rr] * M[(rr * 16 + s2) * 2 + bit];
            nv[s2] = acc;
        }
        #pragma unroll
        for (int s2 = 0; s2 < R; s2++) v[s2] = nv[s2];
    }
    const int xl = xr[31] & 1;
    float acc = 0.f;
    #pragma unroll
    for (int rr = 0; rr < R; rr++) acc += v[rr] * cl[rr * 2 + xl];
    out[b] = acc;
}

extern "C" void kernel_launch(void* const* d_in, const int* in_sizes, int n_in,
                              void* d_out, int out_size, void* d_ws, size_t ws_size,
                              hipStream_t stream) {
    const int* X = (const int*)d_in[0];
    const float* cf = (const float*)d_in[1];
    const float* cm = (const float*)d_in[2];
    const float* cl = (const float*)d_in[3];
    float* out = (float*)d_out;

    // pk array for the fallback path lives after the tables
    const size_t need = ((size_t)WS_FLOATS + BATCH) * sizeof(float);
    if (ws_size >= need) {
        float* ws = (float*)d_ws;
        void* args[] = { (void*)&X, (void*)&cf, (void*)&cm, (void*)&cl,
                         (void*)&ws, (void*)&out };
        hipError_t err = hipLaunchCooperativeKernel((const void*)tt_fused,
                                                    dim3(NBLK), dim3(256),
                                                    args, 0, stream);
        if (err != hipSuccess) {
            unsigned* pk = (unsigned*)(ws + WS_FLOATS);
            tt_stage1<<<1024, 256, 0, stream>>>(X, cf, cm, cl, ws, pk);
            tt_stage2<<<512, 256, 0, stream>>>(ws);
            tt_gather<<<BATCH / 256, 256, 0, stream>>>(ws, pk, out);
        }
    } else {
        tt_direct<<<(BATCH + 255) / 256, 256, 0, stream>>>(X, cf, cm, cl, out);
    }
}

// Round 6
// 111.819 us; speedup vs baseline: 3.0946x; 3.0946x over previous
//
#include <hip/hip_runtime.h>

// TensorTrain: out[b] = first(x0) . M0(x1) . ... . M29(x30) . last(x31)
// with R=16, D=32, B=262144, selection bits in {0,1}.
//
// Meet-in-the-middle: out = V16[p] . W16[s], p = x0..x15 (MSB first),
// s = x16..x31. TWO dispatches (round-3 structure, best measured 111.4 us;
// round-5 proved cooperative grid.sync costs ~130 us each on 8 XCDs — dead
// end).  This round folds the X bit-pack into the build kernel so the 33.5
// MB X stream overlaps the table math, and the second kernel reads a 4 B
// packed index instead of 128 B of X.
//   d1 tt_build_pack (512 blocks): block packs its own 512 elements -> pk;
//      blocks 0..255 build V16 slice, 256..511 build W16 slice from
//      bit-deinterleaved LDS-staged cores (rolled loops: round-2's 90 KB
//      straight-line bodies were I-fetch-bound at 7% VALUBusy).
//   d2 tt_gather (1024 blocks): pk read, two 64 B gathers, 16-wide dot.

#define R 16
#define TT_D 32
#define BATCH 262144

// workspace layout, in floats
#define OFF_V16  0                      // 65536 x 16  (4 MB)
#define OFF_W16  1048576                // 65536 x 16  (4 MB)
#define OFF_PK   2097152                // BATCH u32 packed indices (1 MB)
#define WS_FLOATS (OFF_PK + BATCH)      // ~9 MB

// LDS padding: nibble-table stride 268 floats (268 % 32 = 12 -> the 4
// distinct rows a wave touches land on distinct banks; 256 would be 4-way).
#define MSTRIDE 268
#define VSTRIDE 17

// u (registers, row-vec) = u @ M, M row-major 16x16 in LDS.
// Inner fully unrolled: static indexing keeps u/nv in VGPRs.
__device__ __forceinline__ void rowvec_mat(const float* __restrict__ M,
                                           float* __restrict__ u) {
    float nv[R];
    #pragma unroll
    for (int s = 0; s < R; s++) nv[s] = 0.f;
    #pragma unroll
    for (int t2 = 0; t2 < R; t2++) {
        const float a = u[t2];
        #pragma unroll
        for (int s = 0; s < R; s++) nv[s] += a * M[t2 * 16 + s];
    }
    #pragma unroll
    for (int s = 0; s < R; s++) u[s] = nv[s];
}

// w (registers, col-vec) = M @ w.
__device__ __forceinline__ void mat_colvec(const float* __restrict__ M,
                                           float* __restrict__ w) {
    float nw[R];
    #pragma unroll
    for (int r2 = 0; r2 < R; r2++) {
        float a = 0.f;
        #pragma unroll
        for (int k = 0; k < R; k++) a += M[r2 * 16 + k] * w[k];
        nw[r2] = a;
    }
    #pragma unroll
    for (int r2 = 0; r2 < R; r2++) w[r2] = nw[r2];
}

// Row r of M[lbase](b0) @ M[lbase+1](b1) @ M[lbase+2](b2) @ M[lbase+3](b3),
// bits of e MSB-first. scm layout: [core][bit][r*16+s], 512 floats/core.
__device__ __forceinline__ void chain4_row(const float* __restrict__ scm, int lbase,
                                           int e, int r, float* __restrict__ u) {
    const float* M0 = scm + lbase * 512 + ((e >> 3) & 1) * 256;
    #pragma unroll
    for (int s = 0; s < R; s++) u[s] = M0[r * 16 + s];
    for (int k = 1; k <= 3; k++) {
        const float* M = scm + (lbase + k) * 512 + ((e >> (3 - k)) & 1) * 256;
        rowvec_mat(M, u);
    }
}

// Pack one element's 32 bits into (p<<16)|s, MSB-first per half.
__device__ __forceinline__ unsigned pack_elem(const int* __restrict__ X, int b) {
    const int4* Xr = (const int4*)(X + (size_t)b * TT_D);
    unsigned v = 0;
    #pragma unroll
    for (int q = 0; q < 8; q++) {
        const int4 c = Xr[q];
        v = (v << 4) | ((unsigned)(c.x & 1) << 3) | ((unsigned)(c.y & 1) << 2)
                     | ((unsigned)(c.z & 1) << 1) | (unsigned)(c.w & 1);
    }
    return v;
}

// ---------------------------------------------------------------------------
// d1: pack own 512 elements + build table slice (round-3 build verbatim).
__global__ __launch_bounds__(256) void tt_build_pack(const int* __restrict__ X,
                                                     const float* __restrict__ cf,
                                                     const float* __restrict__ cm,
                                                     const float* __restrict__ cl,
                                                     float* __restrict__ ws,
                                                     unsigned* __restrict__ pk) {
    __shared__ float scm[15 * 512];     // staged cores, bit-deinterleaved (30 KB)
    __shared__ float T0[16 * MSTRIDE];  // prefix: B=M7..10 ; suffix: F=M23..26
    __shared__ float T1[16 * MSTRIDE];  // prefix: C=M11..14; suffix: W4 vecs (VSTRIDE)
    __shared__ float SA[16 * VSTRIDE];  // suffix: Dm[h>>4] rows
    __shared__ float SE[16 * VSTRIDE];  // suffix: E[h&15] rows
    __shared__ float SV[16];            // prefix: v8 = first@M0..M6
    __shared__ float SG[256];           // suffix: G = Dm @ E

    const int t = threadIdx.x;
    const int e = t >> 4, r = t & 15;
    const bool isPrefix = (blockIdx.x < 256);
    const int h = isPrefix ? blockIdx.x : (blockIdx.x - 256);

    // ---- phase A: pack this block's 512 elements (overlaps table math) ----
    {
        const int base = (int)blockIdx.x * 512;
        pk[base + t]       = pack_elem(X, base + t);
        pk[base + 256 + t] = pack_elem(X, base + 256 + t);
    }

    // ---- phase 0: stage this half's 15 cores into LDS, bit-deinterleaved ----
    {
        const float2* cm2 = (const float2*)(cm + (isPrefix ? 0 : 15) * 512);
        for (int j = t; j < 15 * 256; j += 256) {
            const float2 vv = cm2[j];                 // coalesced 8B loads
            const int ci = j >> 8, idx = j & 255;
            scm[ci * 512 + idx] = vv.x;               // bit 0 plane
            scm[ci * 512 + 256 + idx] = vv.y;         // bit 1 plane
        }
    }
    __syncthreads();

    if (isPrefix) {
        // ---- phase 1a: wave0 lanes 0-15, column-parallel v8 chain ----
        // v8 = first(x0).M0(x1)...M6(x7), x0 = h>>7, M_j bit = (h>>(6-j))&1.
        if (t < 16) {
            SV[t] = cf[t * 2 + ((h >> 7) & 1)];
            for (int j = 0; j < 7; j++) {
                const float* M = scm + j * 512 + (((h >> (6 - j)) & 1) << 8);
                float a = 0.f;
                #pragma unroll
                for (int t2 = 0; t2 < R; t2++) a += SV[t2] * M[t2 * 16 + t];
                SV[t] = a;   // single wave: all lane reads precede this write
            }
        }
        // ---- phase 1b: nibble tables B (x8..11) -> T0, C (x12..15) -> T1 ----
        {
            float u[R];
            for (int tab = 0; tab < 2; tab++) {
                chain4_row(scm, 7 + 4 * tab, e, r, u);
                float* dst = (tab ? T1 : T0) + e * MSTRIDE + r * 16;
                #pragma unroll
                for (int s = 0; s < R; s++) dst[s] = u[s];
            }
        }
        __syncthreads();
        // ---- phase 2: V16[h*256+t] = v8 @ B[t>>4] @ C[t&15] ----
        float v[R];
        #pragma unroll
        for (int k = 0; k < R; k++) v[k] = SV[k];     // broadcast
        const float* src = T0 + (t >> 4) * MSTRIDE;
        for (int q = 0; q < 2; q++) {
            rowvec_mat(src, v);
            src = T1 + (t & 15) * MSTRIDE;
        }
        float* o = ws + OFF_V16 + (size_t)(h * 256 + t) * 16;
        #pragma unroll
        for (int s = 0; s < R; s++) o[s] = v[s];
    } else {
        // local core index = global - 15: Dm(M15..18)=0, E(M19..22)=4,
        // F(M23..26)=8, M27..29 -> 12..14.
        // ---- phase 1: F rows by all threads; Dm/E rows by t in [16,48);
        //               W4 vectors by t in [48,64) ----
        {
            float u[R];
            for (int job = 0; job < 2; job++) {
                int lb, ee, rr;
                float* dst;
                bool active = true;
                if (job == 0)      { lb = 8; ee = e;      rr = r;      dst = T0 + e * MSTRIDE + r * 16; }
                else if (t < 16)   { lb = 0; ee = h >> 4; rr = t;      dst = SA + t * VSTRIDE; }
                else if (t < 32)   { lb = 4; ee = h & 15; rr = t - 16; dst = SE + (t - 16) * VSTRIDE; }
                else               { active = false; lb = 0; ee = 0; rr = 0; dst = nullptr; }
                if (active) {
                    chain4_row(scm, lb, ee, rr, u);
                    #pragma unroll
                    for (int s = 0; s < R; s++) dst[s] = u[s];
                }
            }
        }
        if (t >= 48 && t < 64) {                      // W4[l] = M27(l3)M28(l2)M29(l1).last(l0)
            const int l = t - 48;
            float w[R];
            #pragma unroll
            for (int r2 = 0; r2 < R; r2++) w[r2] = cl[r2 * 2 + (l & 1)];
            for (int k = 0; k < 3; k++) {             // M29, M28, M27
                const float* M = scm + (14 - k) * 512 + (((l >> (k + 1)) & 1) << 8);
                mat_colvec(M, w);
            }
            float* dst = T1 + l * VSTRIDE;
            #pragma unroll
            for (int r2 = 0; r2 < R; r2++) dst[r2] = w[r2];
        }
        __syncthreads();
        // ---- phase 2: G = Dm[h>>4] @ E[h&15] (one element per thread) ----
        {
            const int gr = t >> 4, gc = t & 15;
            float a = 0.f;
            #pragma unroll
            for (int k = 0; k < R; k++) a += SA[gr * VSTRIDE + k] * SE[k * VSTRIDE + gc];
            SG[gr * 16 + gc] = a;
        }
        __syncthreads();
        // ---- phase 3: W16[h*256+t] = G @ (F[t>>4] @ W4[t&15]) ----
        float w[R];
        #pragma unroll
        for (int k = 0; k < R; k++) w[k] = T1[(t & 15) * VSTRIDE + k];
        const float* src = T0 + (t >> 4) * MSTRIDE;
        for (int q = 0; q < 2; q++) {
            mat_colvec(src, w);
            src = SG;
        }
        float* o = ws + OFF_W16 + (size_t)(h * 256 + t) * 16;
        #pragma unroll
        for (int r2 = 0; r2 < R; r2++) o[r2] = w[r2];
    }
}

// ---------------------------------------------------------------------------
// d2: per element: 4 B packed index read, two 64 B gathers, 16-wide dot.
__global__ __launch_bounds__(256) void tt_gather(const float* __restrict__ ws,
                                                 const unsigned* __restrict__ pk,
                                                 float* __restrict__ out) {
    const int b = blockIdx.x * 256 + threadIdx.x;
    const unsigned v2 = pk[b];
    const float4* v = (const float4*)(ws + OFF_V16 + (size_t)(v2 >> 16) * 16);
    const float4* w = (const float4*)(ws + OFF_W16 + (size_t)(v2 & 0xffffu) * 16);
    float acc = 0.f;
    #pragma unroll
    for (int k = 0; k < 4; k++) {
        const float4 a = v[k], c = w[k];
        acc += a.x * c.x + a.y * c.y + a.z * c.z + a.w * c.w;
    }
    out[b] = acc;
}

// ---------------------------------------------------------------------------
// Fallback: direct per-thread chain (used only if ws too small).
__global__ __launch_bounds__(256) void tt_direct(const int* __restrict__ X,
                                                 const float* __restrict__ cf,
                                                 const float* __restrict__ cm,
                                                 const float* __restrict__ cl,
                                                 float* __restrict__ out) {
    __shared__ float scm[30 * 16 * 16 * 2];
    for (int i = threadIdx.x; i < 30 * 16 * 16 * 2; i += blockDim.x) scm[i] = cm[i];
    __syncthreads();
    const int b = blockIdx.x * blockDim.x + threadIdx.x;
    if (b >= BATCH) return;
    const int* xr = X + (size_t)b * TT_D;
    float v[R], nv[R];
    const int x0 = xr[0] & 1;
    #pragma unroll
    for (int rr = 0; rr < R; rr++) v[rr] = cf[rr * 2 + x0];
    for (int i = 1; i <= 30; i++) {
        const int bit = xr[i] & 1;
        const float* M = scm + (i - 1) * 512;
        #pragma unroll
        for (int s2 = 0; s2 < R; s2++) {
            float acc = 0.f;
            #pragma unroll
            for (int rr = 0; rr < R; rr++) acc += v[rr] * M[(rr * 16 + s2) * 2 + bit];
            nv[s2] = acc;
        }
        #pragma unroll
        for (int s2 = 0; s2 < R; s2++) v[s2] = nv[s2];
    }
    const int xl = xr[31] & 1;
    float acc = 0.f;
    #pragma unroll
    for (int rr = 0; rr < R; rr++) acc += v[rr] * cl[rr * 2 + xl];
    out[b] = acc;
}

extern "C" void kernel_launch(void* const* d_in, const int* in_sizes, int n_in,
                              void* d_out, int out_size, void* d_ws, size_t ws_size,
                              hipStream_t stream) {
    const int* X = (const int*)d_in[0];
    const float* cf = (const float*)d_in[1];
    const float* cm = (const float*)d_in[2];
    const float* cl = (const float*)d_in[3];
    float* out = (float*)d_out;

    if (ws_size >= (size_t)WS_FLOATS * sizeof(float)) {
        float* ws = (float*)d_ws;
        unsigned* pk = (unsigned*)(ws + OFF_PK);
        tt_build_pack<<<512, 256, 0, stream>>>(X, cf, cm, cl, ws, pk);
        tt_gather<<<BATCH / 256, 256, 0, stream>>>(ws, pk, out);
    } else {
        tt_direct<<<(BATCH + 255) / 256, 256, 0, stream>>>(X, cf, cm, cl, out);
    }
}